// Round 12
// baseline (519.931 us; speedup 1.0000x reference)
//
#include <hip/hip_runtime.h>

typedef unsigned short u16;
typedef __attribute__((ext_vector_type(8))) short short8;    // 8 x 16-bit payload
typedef __attribute__((ext_vector_type(4))) short s16x4;
typedef __attribute__((ext_vector_type(8))) _Float16 half8;  // MFMA f16 A/B frag
typedef __attribute__((ext_vector_type(4))) float f32x4;
typedef __attribute__((ext_vector_type(16))) float f32x16;
typedef __attribute__((ext_vector_type(4))) unsigned int u32x4;

#define DEVI static __device__ __forceinline__

static constexpr int B_ = 4, N_ = 2048, C_ = 1024, H_ = 16, D_ = 64;
static constexpr int M_ = B_ * N_;   // 8192
static constexpr int C3 = 3072;      // qkv row stride (3C)

DEVI u16 f2h(float f) {
  _Float16 h = (_Float16)f;          // v_cvt_f16_f32, RTN
  return __builtin_bit_cast(u16, h);
}

DEVI unsigned pk2h(float lo, float hi) {  // pack 2 f32 -> 2 f16 (lo in [15:0])
  return __builtin_bit_cast(unsigned, __builtin_amdgcn_cvt_pkrtz(lo, hi));
}

DEVI void gload_lds16(const void* g, void* lds) {
  __builtin_amdgcn_global_load_lds(
      (const __attribute__((address_space(1))) unsigned int*)g,
      (__attribute__((address_space(3))) unsigned int*)lds, 16, 0, 0);
}

// f32 -> f16 cast, 8 elems/thread
__global__ __launch_bounds__(256) void f32_to_f16(const float* __restrict__ src,
                                                  u16* __restrict__ dst, int n8) {
  int idx = blockIdx.x * 256 + threadIdx.x;
  if (idx >= n8) return;
  const float* s = src + (size_t)idx * 8;
  f32x4 f0 = *(const f32x4*)s;
  f32x4 f1 = *(const f32x4*)(s + 4);
  short8 o;
#pragma unroll
  for (int j = 0; j < 8; ++j) o[j] = (short)f2h(j < 4 ? f0[j] : f1[j - 4]);
  *(short8*)(dst + (size_t)idx * 8) = o;
}

// C[M][Nout] = A[M][1024] * B[Nout][1024]^T + bias.  128x128 tile, BK=32, 4 waves.
template <bool OUT_F16>
__global__ __launch_bounds__(256) void gemm_bt(const u16* __restrict__ A,
                                               const u16* __restrict__ Bm,
                                               const float* __restrict__ bias,
                                               void* __restrict__ outp, int Nout) {
  __shared__ u16 As[128 * 32];
  __shared__ u16 Bs[128 * 32];
  const int tid = threadIdx.x;
  const int w = tid >> 6, l = tid & 63;
  const int wr = w >> 1, wc = w & 1;
  const int l15 = l & 15, lg = l >> 4;
  const int nx = gridDim.x;
  int bid = blockIdx.y * nx + blockIdx.x;
  int cpx = (nx * gridDim.y) >> 3;
  int swz = (bid & 7) * cpx + (bid >> 3);
  int bx = swz % nx, by = swz / nx;
  const u16* Ab = A + (size_t)(bx * 128) * C_;
  const u16* Bb = Bm + (size_t)(by * 128) * C_;
  const int arow = tid >> 2, ac8 = (tid & 3) * 8;
  f32x4 acc[4][4];
#pragma unroll
  for (int m = 0; m < 4; ++m)
#pragma unroll
    for (int n = 0; n < 4; ++n) acc[m][n] = (f32x4){0.f, 0.f, 0.f, 0.f};

  for (int kt = 0; kt < C_; kt += 32) {
    __syncthreads();
#pragma unroll
    for (int i = 0; i < 2; ++i) {
      gload_lds16(Ab + (size_t)(i * 64 + arow) * C_ + kt + ac8,
                  (char*)As + (i * 64 + w * 16) * 64);
      gload_lds16(Bb + (size_t)(i * 64 + arow) * C_ + kt + ac8,
                  (char*)Bs + (i * 64 + w * 16) * 64);
    }
    __syncthreads();
    half8 af[4], bf[4];
#pragma unroll
    for (int m = 0; m < 4; ++m)
      af[m] = __builtin_bit_cast(half8, *(const short8*)((const char*)As +
                  (wr * 64 + m * 16 + l15) * 64 + lg * 16));
#pragma unroll
    for (int n = 0; n < 4; ++n)
      bf[n] = __builtin_bit_cast(half8, *(const short8*)((const char*)Bs +
                  (wc * 64 + n * 16 + l15) * 64 + lg * 16));
#pragma unroll
    for (int m = 0; m < 4; ++m)
#pragma unroll
      for (int n = 0; n < 4; ++n)
        acc[m][n] = __builtin_amdgcn_mfma_f32_16x16x32_f16(af[m], bf[n], acc[m][n], 0, 0, 0);
  }
#pragma unroll
  for (int m = 0; m < 4; ++m)
#pragma unroll
    for (int n = 0; n < 4; ++n) {
      int col = by * 128 + wc * 64 + n * 16 + l15;
      float bval = bias[col];
#pragma unroll
      for (int i = 0; i < 4; ++i) {
        int row = bx * 128 + wr * 64 + m * 16 + lg * 4 + i;
        float v = acc[m][n][i] + bval;
        if (OUT_F16)
          ((u16*)outp)[(size_t)row * Nout + col] = f2h(v);
        else
          ((float*)outp)[(size_t)row * Nout + col] = v;
      }
    }
}

// K fragment pre-pack: kf chunk g (16B) holds K[key = kh*32 + l31][d-slice (df*2+hi)*8]
// g = ((((bh*32 + t)*2 + kh)*4 + df)*64 + l)
__global__ __launch_bounds__(256) void kfrag_prep(const u16* __restrict__ qkv,
                                                  u16* __restrict__ kf) {
  int g = blockIdx.x * 256 + threadIdx.x;
  int l = g & 63;
  int df = (g >> 6) & 3;
  int kh = (g >> 8) & 1;
  int t = (g >> 9) & 31;
  int bh = g >> 14;
  int b = bh >> 4, h = bh & 15;
  const u16* src = qkv + (size_t)(b * N_ + t * 64 + kh * 32 + (l & 31)) * C3 +
                   C_ + h * D_ + (df * 2 + (l >> 5)) * 8;
  *(short8*)(kf + (size_t)g * 8) = *(const short8*)src;
}

// V fragment pre-pack (transpose + REGISTER-ORDER key permutation):
// vf chunk (vh,kc) elem jj holds V^T[d = vh*32 + l31][key = kc*16 + (jj&3) + 8*(jj>>2) + 4*hi]
// chunk = ((((bh*32 + t)*2 + vh)*4 + kc)*64 + l)   [vh*4+kc = combo]
__global__ __launch_bounds__(256) void vfrag_prep(const u16* __restrict__ qkv,
                                                  u16* __restrict__ vf) {
  __shared__ u16 tile[64][72];
  const int tid = threadIdx.x;
  const int bh = blockIdx.y, b = bh >> 4, h = bh & 15;
  const int t = blockIdx.x;
  const int r = tid >> 3, c8 = (tid & 7) * 8;
#pragma unroll
  for (int rr = 0; rr < 2; ++rr) {
    int row = rr * 32 + r;
    short8 v = *(const short8*)(qkv + (size_t)(b * N_ + t * 64 + row) * C3 +
                                2 * C_ + h * D_ + c8);
    *(short8*)&tile[row][c8] = v;
  }
  __syncthreads();
  const int l = tid & 63, wv = tid >> 6;
  const int l31 = l & 31, hi = l >> 5;
#pragma unroll
  for (int i = 0; i < 2; ++i) {
    int combo = wv * 2 + i;
    int vh = combo >> 2, kc = combo & 3;
    short8 o;
#pragma unroll
    for (int jj = 0; jj < 8; ++jj)
      o[jj] = (short)tile[kc * 16 + (jj & 3) + 8 * (jj >> 2) + 4 * hi][vh * 32 + l31];
    *(short8*)(vf + ((size_t)(bh * 32 + t) * 8 + combo) * 512 + l * 8) = o;
  }
}

// Flash attention (fp16, static-max softmax, NO LDS / NO barriers).
// 64 q-rows per wave (two q-sets A/B share every K/V fragment read).
// Round 12: explicit 1-stage software pipeline — K(t+1) issued after QK-B,
// V(t+1) issued after PV — via a manually 2x-unrolled loop with NAMED buffer
// pairs (no dynamic indexing, no copies). __launch_bounds__(256,2) frees the
// register allocator to ~256 VGPR (grid supplies only 2 waves/SIMD anyway).
// Block = 4 independent waves x 64 q = 256 q. Grid (8, 64) XCD-swizzled.
__global__ __launch_bounds__(256, 2) void attn_fused(const u16* __restrict__ qkv,
                                                     const u16* __restrict__ kf,
                                                     const u16* __restrict__ vf,
                                                     u16* __restrict__ att) {
  const int tid = threadIdx.x;
  const int w = tid >> 6, l = tid & 63;
  const int l31 = l & 31, hi = l >> 5;
  int bid = blockIdx.y * gridDim.x + blockIdx.x;
  int swz = (bid & 7) * 64 + (bid >> 3);       // 512 blocks -> 64 per XCD
  const int qt = swz & 7, bh = swz >> 3;
  const int b = bh >> 4, h = bh & 15;
  const int qb = qt * 256 + w * 64;            // wave covers q [qb, qb+64)

  const float sc2 = 0.125f * 1.4426950408889634f;  // scale * log2(e)
  half8 qfA[4], qfB[4];
  {
    const _Float16 sch = (_Float16)sc2;
    const u16* qrowA = qkv + (size_t)(b * N_ + qb + l31) * C3 + h * D_ + hi * 8;
    const u16* qrowB = qrowA + (size_t)32 * C3;
#pragma unroll
    for (int df = 0; df < 4; ++df) {
      half8 qa = __builtin_bit_cast(half8, *(const short8*)(qrowA + df * 16));
      half8 qc = __builtin_bit_cast(half8, *(const short8*)(qrowB + df * 16));
#pragma unroll
      for (int j = 0; j < 8; ++j) { qa[j] *= sch; qc[j] *= sch; }
      qfA[df] = qa;
      qfB[df] = qc;
    }
  }

  f32x16 aA0, aA1, aB0, aB1;  // O^T tiles per set (d 0..31 / 32..63), col q = l31
#pragma unroll
  for (int j = 0; j < 16; ++j) { aA0[j] = 0.f; aA1[j] = 0.f; aB0[j] = 0.f; aB1[j] = 0.f; }
  float lrowA = 0.f, lrowB = 0.f;

  const u16* kp = kf + (size_t)bh * 32 * 4096;
  const u16* vp = vf + (size_t)bh * 32 * 4096;
  const int loff = l * 8;

#define MKPF(SV, J0, OUT)                                                      \
  {                                                                            \
    u32x4 wq = {pk2h(SV[J0 + 0], SV[J0 + 1]), pk2h(SV[J0 + 2], SV[J0 + 3]),   \
                pk2h(SV[J0 + 4], SV[J0 + 5]), pk2h(SV[J0 + 6], SV[J0 + 7])};   \
    OUT = __builtin_bit_cast(half8, wq);                                       \
  }

#define LOADK(DST, TT)                                                         \
  _Pragma("unroll") for (int kh_ = 0; kh_ < 2; ++kh_)                          \
  _Pragma("unroll") for (int df_ = 0; df_ < 4; ++df_)                          \
    DST[kh_][df_] = __builtin_bit_cast(half8, *(const short8*)(                \
        kp + (size_t)(TT)*4096 + ((kh_ * 4 + df_) * 64) * 8 + loff));

#define LOADV(DST, TT)                                                         \
  _Pragma("unroll") for (int vh_ = 0; vh_ < 2; ++vh_)                          \
  _Pragma("unroll") for (int kc_ = 0; kc_ < 4; ++kc_)                          \
    DST[vh_][kc_] = __builtin_bit_cast(half8, *(const short8*)(                \
        vp + (size_t)(TT)*4096 + ((vh_ * 4 + kc_) * 64) * 8 + loff));

// One KV tile: consumes KC/VC (tile T), prefetches KN/VN (tile T+1).
#define TILE(T, KC, VC, KN, VN)                                                \
  {                                                                            \
    f32x16 s0, s1;                                                             \
    _Pragma("unroll") for (int j = 0; j < 16; ++j) { s0[j] = 0.f; s1[j] = 0.f; } \
    __builtin_amdgcn_s_setprio(1);                                             \
    _Pragma("unroll") for (int df = 0; df < 4; ++df) {                         \
      s0 = __builtin_amdgcn_mfma_f32_32x32x16_f16(KC[0][df], qfA[df], s0, 0, 0, 0); \
      s1 = __builtin_amdgcn_mfma_f32_32x32x16_f16(KC[1][df], qfA[df], s1, 0, 0, 0); \
    }                                                                          \
    __builtin_amdgcn_s_setprio(0);                                             \
    float su[4] = {0.f, 0.f, 0.f, 0.f};                                        \
    _Pragma("unroll") for (int j = 0; j < 16; ++j) {                           \
      s0[j] = __builtin_amdgcn_exp2f(s0[j]); su[j & 3] += s0[j]; }             \
    _Pragma("unroll") for (int j = 0; j < 16; ++j) {                           \
      s1[j] = __builtin_amdgcn_exp2f(s1[j]); su[j & 3] += s1[j]; }             \
    lrowA += (su[0] + su[1]) + (su[2] + su[3]);                                \
    half8 pA0, pA1, pA2, pA3;                                                  \
    MKPF(s0, 0, pA0) MKPF(s0, 8, pA1) MKPF(s1, 0, pA2) MKPF(s1, 8, pA3)        \
    f32x16 z0, z1;                                                             \
    _Pragma("unroll") for (int j = 0; j < 16; ++j) { z0[j] = 0.f; z1[j] = 0.f; } \
    __builtin_amdgcn_s_setprio(1);                                             \
    _Pragma("unroll") for (int df = 0; df < 4; ++df) {                         \
      z0 = __builtin_amdgcn_mfma_f32_32x32x16_f16(KC[0][df], qfB[df], z0, 0, 0, 0); \
      z1 = __builtin_amdgcn_mfma_f32_32x32x16_f16(KC[1][df], qfB[df], z1, 0, 0, 0); \
    }                                                                          \
    __builtin_amdgcn_s_setprio(0);                                             \
    if ((T) + 1 < 32) { LOADK(KN, (T) + 1) }                                   \
    float sv[4] = {0.f, 0.f, 0.f, 0.f};                                        \
    _Pragma("unroll") for (int j = 0; j < 16; ++j) {                           \
      z0[j] = __builtin_amdgcn_exp2f(z0[j]); sv[j & 3] += z0[j]; }             \
    _Pragma("unroll") for (int j = 0; j < 16; ++j) {                           \
      z1[j] = __builtin_amdgcn_exp2f(z1[j]); sv[j & 3] += z1[j]; }             \
    lrowB += (sv[0] + sv[1]) + (sv[2] + sv[3]);                                \
    half8 pB0, pB1, pB2, pB3;                                                  \
    MKPF(z0, 0, pB0) MKPF(z0, 8, pB1) MKPF(z1, 0, pB2) MKPF(z1, 8, pB3)        \
    __builtin_amdgcn_s_setprio(1);                                             \
    aA0 = __builtin_amdgcn_mfma_f32_32x32x16_f16(VC[0][0], pA0, aA0, 0, 0, 0); \
    aA1 = __builtin_amdgcn_mfma_f32_32x32x16_f16(VC[1][0], pA0, aA1, 0, 0, 0); \
    aB0 = __builtin_amdgcn_mfma_f32_32x32x16_f16(VC[0][0], pB0, aB0, 0, 0, 0); \
    aB1 = __builtin_amdgcn_mfma_f32_32x32x16_f16(VC[1][0], pB0, aB1, 0, 0, 0); \
    aA0 = __builtin_amdgcn_mfma_f32_32x32x16_f16(VC[0][1], pA1, aA0, 0, 0, 0); \
    aA1 = __builtin_amdgcn_mfma_f32_32x32x16_f16(VC[1][1], pA1, aA1, 0, 0, 0); \
    aB0 = __builtin_amdgcn_mfma_f32_32x32x16_f16(VC[0][1], pB1, aB0, 0, 0, 0); \
    aB1 = __builtin_amdgcn_mfma_f32_32x32x16_f16(VC[1][1], pB1, aB1, 0, 0, 0); \
    aA0 = __builtin_amdgcn_mfma_f32_32x32x16_f16(VC[0][2], pA2, aA0, 0, 0, 0); \
    aA1 = __builtin_amdgcn_mfma_f32_32x32x16_f16(VC[1][2], pA2, aA1, 0, 0, 0); \
    aB0 = __builtin_amdgcn_mfma_f32_32x32x16_f16(VC[0][2], pB2, aB0, 0, 0, 0); \
    aB1 = __builtin_amdgcn_mfma_f32_32x32x16_f16(VC[1][2], pB2, aB1, 0, 0, 0); \
    aA0 = __builtin_amdgcn_mfma_f32_32x32x16_f16(VC[0][3], pA3, aA0, 0, 0, 0); \
    aA1 = __builtin_amdgcn_mfma_f32_32x32x16_f16(VC[1][3], pA3, aA1, 0, 0, 0); \
    aB0 = __builtin_amdgcn_mfma_f32_32x32x16_f16(VC[0][3], pB3, aB0, 0, 0, 0); \
    aB1 = __builtin_amdgcn_mfma_f32_32x32x16_f16(VC[1][3], pB3, aB1, 0, 0, 0); \
    __builtin_amdgcn_s_setprio(0);                                             \
    if ((T) + 1 < 32) { LOADV(VN, (T) + 1) }                                   \
  }

  half8 kA[2][4], vA[2][4], kB[2][4], vB[2][4];
  LOADK(kA, 0)
  LOADV(vA, 0)
  for (int tt = 0; tt < 16; ++tt) {
    TILE(2 * tt, kA, vA, kB, vB)
    TILE(2 * tt + 1, kB, vB, kA, vA)
  }
#undef TILE
#undef LOADK
#undef LOADV
#undef MKPF

  // epilogue: att[m][C] fp16 = O^T / rowsum for both q-sets
  {
    lrowA += __shfl_xor(lrowA, 32);
    lrowB += __shfl_xor(lrowB, 32);
    float rinvA = 1.0f / lrowA;
    float rinvB = 1.0f / lrowB;
    u16* orowA = att + (size_t)(b * N_ + qb + l31) * C_ + h * D_;
    u16* orowB = orowA + (size_t)32 * C_;
#pragma unroll
    for (int dt = 0; dt < 2; ++dt) {
#pragma unroll
      for (int r2 = 0; r2 < 4; ++r2) {
        int d0 = dt * 32 + r2 * 8 + hi * 4;
        s16x4 hvA, hvB;
#pragma unroll
        for (int i = 0; i < 4; ++i) {
          float vA_ = (dt ? aA1[r2 * 4 + i] : aA0[r2 * 4 + i]) * rinvA;
          float vB_ = (dt ? aB1[r2 * 4 + i] : aB0[r2 * 4 + i]) * rinvB;
          hvA[i] = (short)f2h(vA_);
          hvB[i] = (short)f2h(vB_);
        }
        *(s16x4*)(orowA + d0) = hvA;
        *(s16x4*)(orowB + d0) = hvB;
      }
    }
  }
}

extern "C" void kernel_launch(void* const* d_in, const int* in_sizes, int n_in,
                              void* d_out, int out_size, void* d_ws, size_t ws_size,
                              hipStream_t stream) {
  const float* x = (const float*)d_in[0];
  const float* w_qkv = (const float*)d_in[1];
  const float* b_qkv = (const float*)d_in[2];
  const float* w_proj = (const float*)d_in[3];
  const float* b_proj = (const float*)d_in[4];

  char* ws = (char*)d_ws;
  u16* qkv  = (u16*)(ws + 0);            // 8192*3072*2 = 50331648
  u16* x16  = (u16*)(ws + 50331648);     // 16777216
  u16* wq16 = (u16*)(ws + 67108864);     //  6291456
  u16* wp16 = (u16*)(ws + 73400320);     //  2097152
  u16* kf   = (u16*)(ws + 75497472);     // 16777216  (K fragments)
  u16* vf   = (u16*)(ws + 92274688);     // 16777216  (V fragments)
  u16* att  = (u16*)(ws + 109051904);    // 16777216

  f32_to_f16<<<4096, 256, 0, stream>>>(x, x16, M_ * C_ / 8);
  f32_to_f16<<<1536, 256, 0, stream>>>(w_qkv, wq16, 3 * C_ * C_ / 8);
  f32_to_f16<<<512, 256, 0, stream>>>(w_proj, wp16, C_ * C_ / 8);

  gemm_bt<true><<<dim3(64, 24), 256, 0, stream>>>(x16, wq16, b_qkv, qkv, C3);

  kfrag_prep<<<4096, 256, 0, stream>>>(qkv, kf);
  vfrag_prep<<<dim3(32, 64), 256, 0, stream>>>(qkv, vf);

  attn_fused<<<dim3(8, 64), 256, 0, stream>>>(qkv, kf, vf, att);

  gemm_bt<false><<<dim3(64, 8), 256, 0, stream>>>(att, wp16, b_proj, d_out, C_);
}